// Round 12
// baseline (122.485 us; speedup 1.0000x reference)
//
#include <hip/hip_runtime.h>
#include <cstddef>

#define NB 64
#define NQ 64
#define NK 8192
#define ND 64
#define KPB 256            // pass A: k per block (4 waves x 64 k)
#define KSL 512            // pass B: k per block (4 half-tiles of 128)
#define NSLICE (NK / KSL)  // 16 partial slices per b

typedef __attribute__((ext_vector_type(8))) short short8_t;
typedef __attribute__((ext_vector_type(8))) unsigned short ushort8_t;
typedef __attribute__((ext_vector_type(4))) unsigned short ushort4_t;
typedef __attribute__((ext_vector_type(4))) float float4_t;

static __device__ __forceinline__ unsigned short f2bf(float f) {
    unsigned b = __float_as_uint(f);
    b += 0x7FFFu + ((b >> 16) & 1u);          // RNE
    return (unsigned short)(b >> 16);
}
static __device__ __forceinline__ float bf2f(unsigned short u) {
    return __uint_as_float(((unsigned)u) << 16);
}
static __device__ __forceinline__ void split8(const float* f, short8_t& hi, short8_t& lo) {
#pragma unroll
    for (int j = 0; j < 8; ++j) {
        const unsigned u = __float_as_uint(f[j]);
        hi[j] = (short)(u >> 16);
        const float lof = f[j] - __uint_as_float(u & 0xFFFF0000u);
        lo[j] = (short)(__float_as_uint(lof) >> 16);
    }
}

// ---------------------------------------------------------------------------
// Pass A (unchanged from round 10): MFMA QK^T (bf16 hi/lo 3-term split) +
// inverted softmax. Stores UNNORMALIZED bf16 p to ws, pre-swizzled within
// each 128-k half (16B slot ^= row&7) so pass B stages LDS linearly and
// reads MFMA A-frags conflict-free. rowsum from the ROUNDED values.
// ---------------------------------------------------------------------------
__global__ __launch_bounds__(256, 3) void k_qk_p(
    const float* __restrict__ query,
    const float* __restrict__ key,
    unsigned short* __restrict__ pstore,
    float* __restrict__ rowsum)
{
    __shared__ alignas(16) unsigned short SH[64 * 264];  // Q frags, then p tile
    unsigned short* Qhi = SH;
    unsigned short* Qlo = SH + 64 * 72;

    const int tid  = threadIdx.x;
    const int b    = blockIdx.y;
    const int k0   = blockIdx.x * KPB;
    const int lane = tid & 63;
    const int w    = tid >> 6;
    const int lq   = lane & 15;
    const int lg   = lane >> 4;

    float kf[16];
    {
        const float* kr = key + ((size_t)b * NK + k0 + w * 64 + lq) * ND + lg * 8;
        *reinterpret_cast<float4*>(kf)      = *reinterpret_cast<const float4*>(kr);
        *reinterpret_cast<float4*>(kf + 4)  = *reinterpret_cast<const float4*>(kr + 4);
        *reinterpret_cast<float4*>(kf + 8)  = *reinterpret_cast<const float4*>(kr + 32);
        *reinterpret_cast<float4*>(kf + 12) = *reinterpret_cast<const float4*>(kr + 36);
    }

    {
        const float* qb = query + (size_t)b * NQ * ND;
#pragma unroll
        for (int i = 0; i < 2; ++i) {
            const int o  = tid + 256 * i;
            const int q  = o >> 3;
            const int d0 = (o & 7) * 8;
            float f[8];
            *reinterpret_cast<float4*>(f)     = *reinterpret_cast<const float4*>(qb + q * ND + d0);
            *reinterpret_cast<float4*>(f + 4) = *reinterpret_cast<const float4*>(qb + q * ND + d0 + 4);
            short8_t h, l8;
            split8(f, h, l8);
            const int n    = q >> 4;
            const int l    = (q & 15) | (((d0 >> 3) & 3) << 4);
            const int dh   = d0 >> 5;
            const int base = l * 72 + n * 16 + dh * 8;
            *reinterpret_cast<short8_t*>(&Qhi[base]) = h;
            *reinterpret_cast<short8_t*>(&Qlo[base]) = l8;
        }
    }
    __syncthreads();

    short8_t bhi[4][2], blo[4][2];
#pragma unroll
    for (int n = 0; n < 4; ++n)
#pragma unroll
        for (int dh = 0; dh < 2; ++dh) {
            const int base = lane * 72 + n * 16 + dh * 8;
            bhi[n][dh] = *reinterpret_cast<const short8_t*>(&Qhi[base]);
            blo[n][dh] = *reinterpret_cast<const short8_t*>(&Qlo[base]);
        }
    __syncthreads();                       // Q frags in regs -> SH reusable

    unsigned short* pL = SH;               // p tile [64 q][264 pitch]
    float rsacc[4] = {0.f, 0.f, 0.f, 0.f};

#pragma unroll 1
    for (int s = 0; s < 4; ++s) {
        const int kbase = k0 + w * 64 + s * 16;

        short8_t ahi[2], alo[2];
        split8(kf, ahi[0], alo[0]);
        split8(kf + 8, ahi[1], alo[1]);

        if (s < 3) {
            const float* kr = key + ((size_t)b * NK + kbase + 16 + lq) * ND + lg * 8;
            *reinterpret_cast<float4*>(kf)      = *reinterpret_cast<const float4*>(kr);
            *reinterpret_cast<float4*>(kf + 4)  = *reinterpret_cast<const float4*>(kr + 4);
            *reinterpret_cast<float4*>(kf + 8)  = *reinterpret_cast<const float4*>(kr + 32);
            *reinterpret_cast<float4*>(kf + 12) = *reinterpret_cast<const float4*>(kr + 36);
        }

        float4_t acc[4];
#pragma unroll
        for (int n = 0; n < 4; ++n) acc[n] = (float4_t){0.f, 0.f, 0.f, 0.f};
#pragma unroll
        for (int n = 0; n < 4; ++n)
#pragma unroll
            for (int dh = 0; dh < 2; ++dh) {
                acc[n] = __builtin_amdgcn_mfma_f32_16x16x32_bf16(ahi[dh], bhi[n][dh], acc[n], 0, 0, 0);
                acc[n] = __builtin_amdgcn_mfma_f32_16x16x32_bf16(ahi[dh], blo[n][dh], acc[n], 0, 0, 0);
                acc[n] = __builtin_amdgcn_mfma_f32_16x16x32_bf16(alo[dh], bhi[n][dh], acc[n], 0, 0, 0);
            }

        float m[4], z[4];
#pragma unroll
        for (int r = 0; r < 4; ++r) {
            m[r] = fmaxf(fmaxf(acc[0][r], acc[1][r]), fmaxf(acc[2][r], acc[3][r]));
            m[r] = fmaxf(m[r], __shfl_xor(m[r], 1, 64));
            m[r] = fmaxf(m[r], __shfl_xor(m[r], 2, 64));
            m[r] = fmaxf(m[r], __shfl_xor(m[r], 4, 64));
            m[r] = fmaxf(m[r], __shfl_xor(m[r], 8, 64));
            z[r] = 0.f;
        }
#pragma unroll
        for (int n = 0; n < 4; ++n)
#pragma unroll
            for (int r = 0; r < 4; ++r) {
                acc[n][r] = __expf((acc[n][r] - m[r]) * 0.125f);   // 1/sqrt(64) folded
                z[r] += acc[n][r];
            }
#pragma unroll
        for (int r = 0; r < 4; ++r) {
            z[r] += __shfl_xor(z[r], 1, 64);
            z[r] += __shfl_xor(z[r], 2, 64);
            z[r] += __shfl_xor(z[r], 4, 64);
            z[r] += __shfl_xor(z[r], 8, 64);
            z[r] = 1.f / z[r];
        }

#pragma unroll
        for (int n = 0; n < 4; ++n) {
            ushort4_t u;
            float rs = 0.f;
#pragma unroll
            for (int r = 0; r < 4; ++r) {
                u[r] = f2bf(acc[n][r] * z[r]);    // UNNORMALIZED p, bf16
                rs += bf2f(u[r]);
            }
            *reinterpret_cast<ushort4_t*>(
                &pL[(16 * n + lq) * 264 + w * 64 + s * 16 + lg * 4]) = u;
            rs += __shfl_xor(rs, 16, 64);
            rs += __shfl_xor(rs, 32, 64);
            rsacc[n] += rs;
        }
    }

    if (lg == 0) {
#pragma unroll
        for (int n = 0; n < 4; ++n)
            atomicAdd(&rowsum[b * NQ + lq + 16 * n], rsacc[n]);
    }
    __syncthreads();   // pL complete

    {
        const int cl = tid & 63;
#pragma unroll
        for (int t = 0; t < 16; ++t) {
            const int row = t * 4 + w;
            const ushort4_t u = *reinterpret_cast<const ushort4_t*>(&pL[row * 264 + cl * 4]);
            const int c      = cl * 4;
            const int half   = c >> 7;
            const int slot   = (c & 127) >> 3;
            const int sub    = (c >> 2) & 1;
            const int sp     = slot ^ (row & 7);
            *reinterpret_cast<ushort4_t*>(pstore +
                ((size_t)(b * NQ + row)) * NK + k0 + half * 128 + sp * 8 + sub * 4) = u;
        }
    }
}

// ---------------------------------------------------------------------------
// Pass B: pure streaming. V is NOT staged in LDS (zero cross-wave reuse):
// each lane loads its MFMA B-fragment directly from global (wave covers
// 4x64B sectors/instr; the block's 4 waves consume full 256B lines via L1),
// double-buffered in registers (vfA/vfB, static names) one half-tile ahead.
// p staged linearly in LDS (pre-swizzled by pass A -> conflict-free A-frag
// reads). attn written fp32 (col de-swizzled). Deterministic partials.
// LDS: pLu 16KB + rsL -> 4 blocks/CU.
// ---------------------------------------------------------------------------
template<bool PART>
__global__ __launch_bounds__(256, 4) void k_scale_pv(
    const unsigned short* __restrict__ psrc,
    const float* __restrict__ value,
    const float* __restrict__ rowsum,
    float* __restrict__ attn,
    float* __restrict__ dst)     // partials if PART else out
{
    __shared__ alignas(16) unsigned short pLu[64 * 128];
    __shared__ float rsL[NQ];

    const int tid  = threadIdx.x;
    const int b    = blockIdx.y;
    const int ks   = blockIdx.x;
    const int k0   = ks * KSL;
    const int lane = tid & 63;
    const int w    = tid >> 6;
    const int lq   = lane & 15;
    const int lg   = lane >> 4;

    if (tid < NQ) rsL[tid] = 1.f / (rowsum[b * NQ + tid] + 1e-8f);

    const unsigned short* pg = psrc + (size_t)b * NQ * NK;
    const float* vcol = value + ((size_t)b * NK + k0) * ND + 16 * w + lq;

    ushort8_t rp[4];
    float vfA[32], vfB[32];

#define LOADP(HT)                                                              \
    {                                                                          \
        _Pragma("unroll")                                                      \
        for (int i = 0; i < 4; ++i) {                                          \
            const int idx = tid + 256 * i;                                     \
            rp[i] = *reinterpret_cast<const ushort8_t*>(                       \
                &pg[(size_t)(idx >> 4) * NK + k0 + (HT) * 128 + (idx & 15) * 8]); \
        }                                                                      \
    }

#define LOADV(VF, HT)                                                          \
    {                                                                          \
        _Pragma("unroll")                                                      \
        for (int h = 0; h < 4; ++h) {                                          \
            _Pragma("unroll")                                                  \
            for (int j = 0; j < 8; ++j)                                        \
                VF[h * 8 + j] =                                                \
                    vcol[(size_t)((HT) * 128 + h * 32 + lg * 8 + j) * ND];     \
        }                                                                      \
    }

#define STAGE_P(HT)                                                            \
    {                                                                          \
        _Pragma("unroll")                                                      \
        for (int i = 0; i < 4; ++i) {                                          \
            const int idx  = tid + 256 * i;                                    \
            const int row  = idx >> 4;                                         \
            const int sl   = idx & 15;                                         \
            const int slog = sl ^ (row & 7);                                   \
            const float iv = rsL[row];                                         \
            float f[8];                                                        \
            ushort8_t u;                                                       \
            _Pragma("unroll")                                                  \
            for (int j = 0; j < 8; ++j) {                                      \
                f[j] = bf2f(rp[i][j]) * iv;                                    \
                u[j] = f2bf(f[j]);                                             \
            }                                                                  \
            float* ap = attn + ((size_t)(b * NQ + row)) * NK + k0 +            \
                        (HT) * 128 + slog * 8;                                 \
            *reinterpret_cast<float4*>(ap)     = *reinterpret_cast<float4*>(f);     \
            *reinterpret_cast<float4*>(ap + 4) = *reinterpret_cast<float4*>(f + 4); \
            *reinterpret_cast<ushort8_t*>(&pLu[idx * 8]) = u;                  \
        }                                                                      \
    }

#define PVSTEP(VF)                                                             \
    {                                                                          \
        _Pragma("unroll")                                                      \
        for (int h = 0; h < 4; ++h) {                                          \
            short8_t vb;                                                       \
            _Pragma("unroll")                                                  \
            for (int j = 0; j < 8; ++j) vb[j] = (short)f2bf(VF[h * 8 + j]);    \
            _Pragma("unroll")                                                  \
            for (int n = 0; n < 4; ++n) {                                      \
                const short8_t pa = *reinterpret_cast<const short8_t*>(        \
                    &pLu[(16 * n + lq) * 128 + (((h * 4 + lg) ^ (lq & 7)) * 8)]); \
                oacc[n] = __builtin_amdgcn_mfma_f32_16x16x32_bf16(pa, vb, oacc[n], 0, 0, 0); \
            }                                                                  \
        }                                                                      \
    }

    float4_t oacc[4];
#pragma unroll
    for (int n = 0; n < 4; ++n) oacc[n] = (float4_t){0.f, 0.f, 0.f, 0.f};

    LOADP(0); LOADV(vfA, 0);

    // ---- half-tile 0
    __syncthreads();            // rsL visible
    STAGE_P(0);
    LOADP(1); LOADV(vfB, 1);
    __syncthreads();            // pLu visible
    PVSTEP(vfA);
    // ---- half-tile 1
    __syncthreads();            // pLu reads done
    STAGE_P(1);
    LOADP(2); LOADV(vfA, 2);
    __syncthreads();
    PVSTEP(vfB);
    // ---- half-tile 2
    __syncthreads();
    STAGE_P(2);
    LOADP(3); LOADV(vfB, 3);
    __syncthreads();
    PVSTEP(vfA);
    // ---- half-tile 3
    __syncthreads();
    STAGE_P(3);
    __syncthreads();
    PVSTEP(vfB);

#undef LOADP
#undef LOADV
#undef STAGE_P
#undef PVSTEP

    // ---- epilogue: D row q = 16n+4lg+r, col d = 16w+lq
    if (PART) {
        float* pb = dst + ((size_t)(b * NSLICE + ks)) * (NQ * ND);
#pragma unroll
        for (int n = 0; n < 4; ++n)
#pragma unroll
            for (int r = 0; r < 4; ++r)
                pb[(16 * n + 4 * lg + r) * ND + 16 * w + lq] = oacc[n][r];
    } else {
#pragma unroll
        for (int n = 0; n < 4; ++n)
#pragma unroll
            for (int r = 0; r < 4; ++r)
                atomicAdd(dst + ((size_t)(b * NQ + 16 * n + 4 * lg + r)) * ND + 16 * w + lq,
                          oacc[n][r]);
    }
}

// ---------------------------------------------------------------------------
// Reduce: out[b,q,d] = sum over 16 slices.
// ---------------------------------------------------------------------------
__global__ __launch_bounds__(256) void k_reduce_out(
    const float* __restrict__ partials,
    float* __restrict__ out)
{
    const int b   = blockIdx.y;
    const int idx = blockIdx.x * 256 + threadIdx.x;    // 0..1023 float4 per b
    const float4* pb = reinterpret_cast<const float4*>(partials + (size_t)b * NSLICE * NQ * ND);
    float4 sum = make_float4(0.f, 0.f, 0.f, 0.f);
#pragma unroll
    for (int s = 0; s < NSLICE; ++s) {
        const float4 v = pb[(size_t)s * (NQ * ND / 4) + idx];
        sum.x += v.x; sum.y += v.y; sum.z += v.z; sum.w += v.w;
    }
    reinterpret_cast<float4*>(out + (size_t)b * NQ * ND)[idx] = sum;
}

extern "C" void kernel_launch(void* const* d_in, const int* in_sizes, int n_in,
                              void* d_out, int out_size, void* d_ws, size_t ws_size,
                              hipStream_t stream) {
    const float* query = (const float*)d_in[0];
    const float* key   = (const float*)d_in[1];
    const float* value = (const float*)d_in[2];

    float* out  = (float*)d_out;                        // [B,Q,D]
    float* attn = (float*)d_out + (size_t)NB * NQ * ND; // [B,Q,K]

    const size_t PB_BYTES   = (size_t)NB * NQ * NK * sizeof(unsigned short); // 64 MiB
    const size_t PART_BYTES = (size_t)NB * NSLICE * NQ * ND * sizeof(float); // 16 MiB

    float* rowsum = (float*)d_ws;                               // 16 KB pad
    unsigned short* pbuf = (unsigned short*)((char*)d_ws + 16384);
    float* partials = (float*)((char*)d_ws + 16384 + PB_BYTES);
    const bool part = ws_size >= 16384 + PB_BYTES + PART_BYTES;

    hipMemsetAsync(rowsum, 0, (size_t)NB * NQ * sizeof(float), stream);
    if (!part)
        hipMemsetAsync(out, 0, (size_t)NB * NQ * ND * sizeof(float), stream);

    dim3 gA(NK / KPB, NB);
    k_qk_p<<<gA, 256, 0, stream>>>(query, key, pbuf, rowsum);

    dim3 gB(NK / KSL, NB);
    if (part) {
        k_scale_pv<true><<<gB, 256, 0, stream>>>(pbuf, value, rowsum, attn, partials);
        k_reduce_out<<<dim3(4, NB), 256, 0, stream>>>(partials, out);
    } else {
        k_scale_pv<false><<<gB, 256, 0, stream>>>(pbuf, value, rowsum, attn, out);
    }
}